// Round 8
// baseline (831.281 us; speedup 1.0000x reference)
//
#include <hip/hip_runtime.h>
#include <math.h>

#define D_MODEL 768
#define D_INNER 1536
#define B_SZ 4
#define T_SZ 512
#define ROWS (B_SZ*T_SZ)   // 2048
#define XP_N 80
#define CH 32              // scan chunks
#define CT 16              // T per chunk
#define XS 8               // x_proj split-K factor
#define XKC (D_INNER/XS)   // 192
#define OS 2               // out_proj split-K factor
#define OKC (D_INNER/OS)   // 768
#define MN_OUT (ROWS*768)  // 1572864

typedef __attribute__((ext_vector_type(8))) short bf16x8;
typedef __attribute__((ext_vector_type(4))) float f32x4;

// async global->LDS, 16B per lane, lane-contiguous LDS destination
#define GLL(g, l) __builtin_amdgcn_global_load_lds( \
    (const __attribute__((address_space(1))) void*)(g), \
    (__attribute__((address_space(3))) void*)(l), 16, 0, 0)

__device__ __forceinline__ float sigmoidf_(float x){ return 1.0f/(1.0f+__expf(-x)); }
__device__ __forceinline__ float siluf_(float x){ return x*sigmoidf_(x); }
__device__ __forceinline__ unsigned short f2bf(float f){
  unsigned u = __builtin_bit_cast(unsigned, f);
  u = (u + 0x7FFFu + ((u >> 16) & 1u)) >> 16;   // RNE
  return (unsigned short)u;
}

// ---------------- bf16 MFMA GEMM, 64x128 tile, double-buffered 2-phase ----------
__global__ __launch_bounds__(256) void gemm_bf16(
    const unsigned short* __restrict__ A, const unsigned short* __restrict__ Wb,
    float* __restrict__ C, int M, int N, int K)
{
  __shared__ unsigned short As[2][64*32];    // 2 x 4 KB
  __shared__ unsigned short Ws[2][128*32];   // 2 x 8 KB
  const int tid = threadIdx.x;
  const int bm = blockIdx.y*64, bn = blockIdx.x*128;
  const int wave = tid >> 6, lane = tid & 63;
  const int wn = wave*32;
  const int fr = lane & 15, quad = lane >> 4;
  f32x4 acc[4][2] = {};
  const int chunk = wave*64 + lane;          // 0..255
  const int row0 = chunk >> 2;               // 0..63
  const int khp  = chunk & 3;
  const int khl  = (khp + 4 - ((row0 >> 1) & 3)) & 3;
  const unsigned short* Ag = A  + (size_t)(bm + row0)*K + khl*8;
  const unsigned short* Wg = Wb + (size_t)(bn + row0)*K + khl*8;
  const size_t rstep = (size_t)64*K;
  const int wo = wave*512;

  GLL(Ag,         As[0] + wo);
  GLL(Wg,         Ws[0] + wo);
  GLL(Wg + rstep, Ws[0] + wo + 2048);
  asm volatile("s_waitcnt vmcnt(0)" ::: "memory");
  __builtin_amdgcn_sched_barrier(0);
  __builtin_amdgcn_s_barrier();

  int cur = 0;
  for (int k0 = 0; k0 < K; k0 += 32){
    const int nxt = cur ^ 1;
    if (k0 + 32 < K){                        // prefetch next tile
      GLL(Ag + k0 + 32,         As[nxt] + wo);
      GLL(Wg + k0 + 32,         Ws[nxt] + wo);
      GLL(Wg + rstep + k0 + 32, Ws[nxt] + wo + 2048);
    }
    bf16x8 a[4], b[2];
    #pragma unroll
    for (int i=0;i<4;i++){
      const int row = i*16 + fr;
      a[i] = *(const bf16x8*)(As[cur] + row*32 + (((quad + (row>>1)) & 3)*8));
    }
    #pragma unroll
    for (int j=0;j<2;j++){
      const int row = wn + j*16 + fr;
      b[j] = *(const bf16x8*)(Ws[cur] + row*32 + (((quad + (row>>1)) & 3)*8));
    }
    #pragma unroll
    for (int i=0;i<4;i++)
      #pragma unroll
      for (int j=0;j<2;j++)
        acc[i][j] = __builtin_amdgcn_mfma_f32_16x16x32_bf16(a[i], b[j], acc[i][j], 0, 0, 0);
    asm volatile("s_waitcnt vmcnt(0)" ::: "memory");
    __builtin_amdgcn_sched_barrier(0);
    __builtin_amdgcn_s_barrier();
    cur = nxt;
  }
  #pragma unroll
  for (int i=0;i<4;i++){
    #pragma unroll
    for (int r=0;r<4;r++){
      const int row = bm + i*16 + quad*4 + r;
      float* Cp = C + (size_t)row*N + bn + wn + fr;
      #pragma unroll
      for (int j=0;j<2;j++)
        Cp[j*16] = acc[i][j][r];
    }
  }
}

// ---------------- bf16 MFMA GEMM, split-K=2 (out_proj partials), dbuf 2-phase ----
__global__ __launch_bounds__(256) void gemm_bf16_sk(
    const unsigned short* __restrict__ A, const unsigned short* __restrict__ Wb,
    float* __restrict__ P0, float* __restrict__ P1, int M, int N, int K)
{
  __shared__ unsigned short As[2][64*32];
  __shared__ unsigned short Ws[2][128*32];
  const int tid = threadIdx.x;
  const int bm = blockIdx.y*64, bn = blockIdx.x*128;
  const int s = blockIdx.z;
  const int koff = s*OKC;
  const int wave = tid >> 6, lane = tid & 63;
  const int wn = wave*32;
  const int fr = lane & 15, quad = lane >> 4;
  f32x4 acc[4][2] = {};
  const int chunk = wave*64 + lane;
  const int row0 = chunk >> 2;
  const int khp  = chunk & 3;
  const int khl  = (khp + 4 - ((row0 >> 1) & 3)) & 3;
  const unsigned short* Ag = A  + (size_t)(bm + row0)*K + koff + khl*8;
  const unsigned short* Wg = Wb + (size_t)(bn + row0)*K + koff + khl*8;
  const size_t rstep = (size_t)64*K;
  const int wo = wave*512;

  GLL(Ag,         As[0] + wo);
  GLL(Wg,         Ws[0] + wo);
  GLL(Wg + rstep, Ws[0] + wo + 2048);
  asm volatile("s_waitcnt vmcnt(0)" ::: "memory");
  __builtin_amdgcn_sched_barrier(0);
  __builtin_amdgcn_s_barrier();

  int cur = 0;
  for (int k0 = 0; k0 < OKC; k0 += 32){
    const int nxt = cur ^ 1;
    if (k0 + 32 < OKC){
      GLL(Ag + k0 + 32,         As[nxt] + wo);
      GLL(Wg + k0 + 32,         Ws[nxt] + wo);
      GLL(Wg + rstep + k0 + 32, Ws[nxt] + wo + 2048);
    }
    bf16x8 a[4], b[2];
    #pragma unroll
    for (int i=0;i<4;i++){
      const int row = i*16 + fr;
      a[i] = *(const bf16x8*)(As[cur] + row*32 + (((quad + (row>>1)) & 3)*8));
    }
    #pragma unroll
    for (int j=0;j<2;j++){
      const int row = wn + j*16 + fr;
      b[j] = *(const bf16x8*)(Ws[cur] + row*32 + (((quad + (row>>1)) & 3)*8));
    }
    #pragma unroll
    for (int i=0;i<4;i++)
      #pragma unroll
      for (int j=0;j<2;j++)
        acc[i][j] = __builtin_amdgcn_mfma_f32_16x16x32_bf16(a[i], b[j], acc[i][j], 0, 0, 0);
    asm volatile("s_waitcnt vmcnt(0)" ::: "memory");
    __builtin_amdgcn_sched_barrier(0);
    __builtin_amdgcn_s_barrier();
    cur = nxt;
  }
  float* Cb = (s == 0 ? P0 : P1);
  #pragma unroll
  for (int i=0;i<4;i++){
    #pragma unroll
    for (int r=0;r<4;r++){
      const int row = bm + i*16 + quad*4 + r;
      float* Cp = Cb + (size_t)row*N + bn + wn + fr;
      #pragma unroll
      for (int j=0;j<2;j++)
        Cp[j*16] = acc[i][j][r];
    }
  }
}

// ---------------- input SGEMM with fused transpose ----------------
__global__ __launch_bounds__(256) void sgemm_input(
    const float* __restrict__ x, const float* __restrict__ W,
    const float* __restrict__ bias, float* __restrict__ C)
{
  __shared__ float As[16][64];
  __shared__ float Wsh[16][64];
  const int bm = blockIdx.y*64, bn = blockIdx.x*64;
  const int b = bm >> 9, t0 = bm & (T_SZ-1);   // 64-row tiles never straddle b
  const int tid = threadIdx.x;
  const int tx = tid & 15, ty = tid >> 4;
  const int lm = tid & 63, lk = (tid >> 6) << 2;
  float acc[4][4] = {};
  const float* Wp = W + (size_t)(bn+lm)*256 + lk;
  const float* xb = x + ((size_t)b*256)*512 + t0 + lm;
  for (int k0 = 0; k0 < 256; k0 += 16){
    #pragma unroll
    for (int i=0;i<4;i++)
      As[lk+i][lm] = xb[(size_t)(k0+lk+i)*512];   // coalesced along t
    float4 wv = *(const float4*)(Wp + k0);
    Wsh[lk+0][lm]=wv.x; Wsh[lk+1][lm]=wv.y; Wsh[lk+2][lm]=wv.z; Wsh[lk+3][lm]=wv.w;
    __syncthreads();
    #pragma unroll
    for (int k = 0; k < 16; k++){
      float a[4], w[4];
      #pragma unroll
      for (int i=0;i<4;i++) a[i] = As[k][ty*4+i];
      #pragma unroll
      for (int j=0;j<4;j++) w[j] = Wsh[k][tx*4+j];
      #pragma unroll
      for (int i=0;i<4;i++)
        #pragma unroll
        for (int j=0;j<4;j++)
          acc[i][j] += a[i]*w[j];
    }
    __syncthreads();
  }
  #pragma unroll
  for (int i=0;i<4;i++){
    const int r = bm + ty*4 + i;
    #pragma unroll
    for (int j=0;j<4;j++){
      const int n = bn + tx*4 + j;
      C[(size_t)r*768 + n] = acc[i][j] + bias[n];
    }
  }
}

// ---------------- x_proj split-K with fused causal conv + silu ----------------
__global__ __launch_bounds__(256) void xproj_conv_splitk(
    const float* __restrict__ xz, const float* __restrict__ cw,
    const float* __restrict__ cb, const float* __restrict__ W,
    float* __restrict__ part)
{
  __shared__ float As[16][64];
  __shared__ float Wsh[16][80];
  const int bm = blockIdx.x*64;
  const int s = blockIdx.y;
  const int koff = s*XKC;
  const int tid = threadIdx.x;
  const int tx = tid & 15, ty = tid >> 4;
  const int lm = tid & 63, lk = (tid >> 6) << 2;
  float acc[4][5] = {};
  const int row = bm + lm;
  const int t = row & (T_SZ-1);
  for (int k0 = 0; k0 < XKC; k0 += 16){
    const int d0 = koff + k0 + lk;
    float4 cbv = *(const float4*)(cb + d0);
    float cba[4] = {cbv.x, cbv.y, cbv.z, cbv.w};
    float4 tp3 = *(const float4*)(xz + (size_t)row*3072 + d0);
    float4 tp0 = (t>=3) ? *(const float4*)(xz + (size_t)(row-3)*3072 + d0) : make_float4(0.f,0.f,0.f,0.f);
    float4 tp1 = (t>=2) ? *(const float4*)(xz + (size_t)(row-2)*3072 + d0) : make_float4(0.f,0.f,0.f,0.f);
    float4 tp2 = (t>=1) ? *(const float4*)(xz + (size_t)(row-1)*3072 + d0) : make_float4(0.f,0.f,0.f,0.f);
    float a0[4]={tp0.x,tp0.y,tp0.z,tp0.w}, a1[4]={tp1.x,tp1.y,tp1.z,tp1.w};
    float a2[4]={tp2.x,tp2.y,tp2.z,tp2.w}, a3[4]={tp3.x,tp3.y,tp3.z,tp3.w};
    #pragma unroll
    for (int i=0;i<4;i++){
      const float4 w4 = *(const float4*)(cw + (size_t)(d0+i)*4);
      float a = cba[i];
      a += a0[i]*w4.x; a += a1[i]*w4.y; a += a2[i]*w4.z; a += a3[i]*w4.w;
      As[lk+i][lm] = siluf_(a);
    }
    for (int i = tid; i < 320; i += 256){
      const int wr = i % 80, wk = (i / 80) << 2;
      float4 wv = *(const float4*)(W + (size_t)wr*D_INNER + koff + k0 + wk);
      Wsh[wk+0][wr]=wv.x; Wsh[wk+1][wr]=wv.y; Wsh[wk+2][wr]=wv.z; Wsh[wk+3][wr]=wv.w;
    }
    __syncthreads();
    #pragma unroll
    for (int k = 0; k < 16; k++){
      float a[4], w[5];
      #pragma unroll
      for (int i=0;i<4;i++) a[i] = As[k][ty*4+i];
      #pragma unroll
      for (int j=0;j<5;j++) w[j] = Wsh[k][tx*5+j];
      #pragma unroll
      for (int i=0;i<4;i++)
        #pragma unroll
        for (int j=0;j<5;j++)
          acc[i][j] += a[i]*w[j];
    }
    __syncthreads();
  }
  #pragma unroll
  for (int i=0;i<4;i++){
    const int r = bm + ty*4 + i;
    #pragma unroll
    for (int j=0;j<5;j++){
      const int n = tx*5 + j;
      part[((size_t)s*ROWS + r)*XP_N + n] = acc[i][j];
    }
  }
}

// ---------------- dt_proj (reads split-K partials inline) + B/C reduce ----------------
__global__ __launch_bounds__(256) void dtproj_fused(
    const float* __restrict__ part, const float* __restrict__ W,
    const float* __restrict__ bias, float* __restrict__ delta,
    float* __restrict__ xpbc)
{
  if (blockIdx.x >= 24){
    const int i = ((blockIdx.x - 24)*32 + blockIdx.y)*256 + threadIdx.x;  // 0..65535
    const int r = i >> 5, cc = i & 31;
    float ssum = 0.f;
    #pragma unroll
    for (int s2=0;s2<XS;s2++)
      ssum += part[((size_t)s2*ROWS + r)*XP_N + 48 + cc];
    xpbc[(size_t)r*32 + cc] = ssum;
    return;
  }
  __shared__ float As[16][64];
  __shared__ float Wsh[16][64];
  const int bm = blockIdx.y*64, bn = blockIdx.x*64;
  const int tid = threadIdx.x;
  const int tx = tid & 15, ty = tid >> 4;
  const int lm = tid & 63, lk = (tid >> 6) << 2;
  float acc[4][4] = {};
  const float* Ap = part + (size_t)(bm+lm)*XP_N + lk;
  const float* Wp = W + (size_t)(bn+lm)*48 + lk;
  for (int k0 = 0; k0 < 48; k0 += 16){
    float4 av = make_float4(0.f,0.f,0.f,0.f);
    #pragma unroll
    for (int s2=0;s2<XS;s2++){
      const float4 pv = *(const float4*)(Ap + (size_t)s2*ROWS*XP_N + k0);
      av.x += pv.x; av.y += pv.y; av.z += pv.z; av.w += pv.w;
    }
    float4 wv = *(const float4*)(Wp + k0);
    As[lk+0][lm]=av.x; As[lk+1][lm]=av.y; As[lk+2][lm]=av.z; As[lk+3][lm]=av.w;
    Wsh[lk+0][lm]=wv.x; Wsh[lk+1][lm]=wv.y; Wsh[lk+2][lm]=wv.z; Wsh[lk+3][lm]=wv.w;
    __syncthreads();
    #pragma unroll
    for (int k = 0; k < 16; k++){
      float a[4], w[4];
      #pragma unroll
      for (int i=0;i<4;i++) a[i] = As[k][ty*4+i];
      #pragma unroll
      for (int j=0;j<4;j++) w[j] = Wsh[k][tx*4+j];
      #pragma unroll
      for (int i=0;i<4;i++)
        #pragma unroll
        for (int j=0;j<4;j++)
          acc[i][j] += a[i]*w[j];
    }
    __syncthreads();
  }
  #pragma unroll
  for (int i=0;i<4;i++){
    const int r = bm + ty*4 + i;
    #pragma unroll
    for (int j=0;j<4;j++){
      const int n = bn + tx*4 + j;
      float v = acc[i][j] + bias[n];
      v = (v > 20.f) ? v : log1pf(__expf(v));
      delta[(size_t)r*D_INNER + n] = v;
    }
  }
}

// ---------------- chunked selective scan, n-SPLIT 2-way ----------------
// thread = (d, nh): d = blk.x*128 + tid/2, nh = tid&1 owns states n = nh*8..nh*8+7.
// Lane pairs share d -> dv/xc/zv loads HW-broadcast. 1536 blocks = 6 waves/SIMD.
__global__ __launch_bounds__(256) void scan_pass1(
    const float* __restrict__ delta, const float* __restrict__ xz,
    const float* __restrict__ xpbc, const float* __restrict__ alog,
    const float* __restrict__ cw, const float* __restrict__ cb,
    float* __restrict__ sdvp, float* __restrict__ Hend)
{
  const int tid = threadIdx.x;
  const int d  = blockIdx.x*128 + (tid >> 1);
  const int nh = tid & 1;
  const int b = blockIdx.y, c = blockIdx.z;
  float4 t0 = *(const float4*)(alog + d*16 + nh*8 + 0);
  float4 t1 = *(const float4*)(alog + d*16 + nh*8 + 4);
  float Av[8] = {t0.x,t0.y,t0.z,t0.w,t1.x,t1.y,t1.z,t1.w};
  float h[8];
  #pragma unroll
  for (int n=0;n<8;n++){ Av[n] = -__expf(Av[n]); h[n]=0.f; }
  float sdv = 0.f;
  const size_t row0 = (size_t)b*T_SZ + (size_t)c*CT;
  const float* dp  = delta + row0*D_INNER + d;
  const float* xp0 = xz    + row0*3072 + d;
  const float* bp  = xpbc  + row0*32 + nh*8;
  const float4 cwv = *(const float4*)(cw + (size_t)d*4);
  const float cbv = cb[d];
  float xm3, xm2, xm1;
  if (c == 0){ xm3 = xm2 = xm1 = 0.f; }
  else { xm3 = xp0[-3*3072]; xm2 = xp0[-2*3072]; xm1 = xp0[-1*3072]; }
  #pragma unroll 4
  for (int tt=0; tt<CT; tt++){
    const float dv = dp[(size_t)tt*D_INNER];
    const float xc = xp0[(size_t)tt*3072];
    float ua = cbv;
    ua += xm3*cwv.x; ua += xm2*cwv.y; ua += xm1*cwv.z; ua += xc*cwv.w;
    const float uv = siluf_(ua);
    xm3 = xm2; xm2 = xm1; xm1 = xc;
    const float4 B0 = *(const float4*)(bp + (size_t)tt*32);
    const float4 B1 = *(const float4*)(bp + (size_t)tt*32 + 4);
    const float Bv[8] = {B0.x,B0.y,B0.z,B0.w,B1.x,B1.y,B1.z,B1.w};
    const float du = dv*uv;
    sdv += dv;
    #pragma unroll
    for (int n=0;n<8;n++){
      const float dA = __expf(dv*Av[n]);
      h[n] = dA*h[n] + du*Bv[n];
    }
  }
  if (nh == 0) sdvp[(size_t)(b*CH+c)*D_INNER + d] = sdv;
  float* Hp = Hend + ((size_t)(b*CH+c)*D_INNER + d)*16 + nh*8;
  *(float4*)(Hp+0) = make_float4(h[0],h[1],h[2],h[3]);
  *(float4*)(Hp+4) = make_float4(h[4],h[5],h[6],h[7]);
}

// pass3 n-split, inline chunk-prefix, shfl-pair reduce for the C-dot
__global__ __launch_bounds__(256) void scan_pass3(
    const float* __restrict__ delta, const float* __restrict__ xz,
    const float* __restrict__ xpbc, const float* __restrict__ alog,
    const float* __restrict__ cw, const float* __restrict__ cb,
    const float* __restrict__ Dp, const float* __restrict__ sdvp,
    const float* __restrict__ Hend, unsigned short* __restrict__ yb)
{
  const int tid = threadIdx.x;
  const int d  = blockIdx.x*128 + (tid >> 1);
  const int nh = tid & 1;
  const int b = blockIdx.y, c = blockIdx.z;
  float4 t0 = *(const float4*)(alog + d*16 + nh*8 + 0);
  float4 t1 = *(const float4*)(alog + d*16 + nh*8 + 4);
  float Av[8] = {t0.x,t0.y,t0.z,t0.w,t1.x,t1.y,t1.z,t1.w};
  #pragma unroll
  for (int n=0;n<8;n++) Av[n] = -__expf(Av[n]);
  // inline prefix over prior chunks
  float h[8];
  #pragma unroll
  for (int n=0;n<8;n++) h[n] = 0.f;
  {
    const size_t bases = (size_t)b*CH*D_INNER + d;
    for (int j = 0; j < c; j++){
      const float sdv = sdvp[bases + (size_t)j*D_INNER];
      const float* Hj = Hend + (bases + (size_t)j*D_INNER)*16 + nh*8;
      const float4 H0 = *(const float4*)(Hj+0);
      const float4 H1 = *(const float4*)(Hj+4);
      const float Hv[8] = {H0.x,H0.y,H0.z,H0.w,H1.x,H1.y,H1.z,H1.w};
      #pragma unroll
      for (int n=0;n<8;n++)
        h[n] = __expf(Av[n]*sdv)*h[n] + Hv[n];
    }
  }
  const float Dv = Dp[d];
  const size_t row0 = (size_t)b*T_SZ + (size_t)c*CT;
  const float* dp  = delta + row0*D_INNER + d;
  const float* xp0 = xz    + row0*3072 + d;
  const float* zp  = xz    + row0*3072 + 1536 + d;
  const float* bp  = xpbc  + row0*32 + nh*8;
  unsigned short* yp = yb + row0*D_INNER + d;
  const float4 cwv = *(const float4*)(cw + (size_t)d*4);
  const float cbv = cb[d];
  float xm3, xm2, xm1;
  if (c == 0){ xm3 = xm2 = xm1 = 0.f; }
  else { xm3 = xp0[-3*3072]; xm2 = xp0[-2*3072]; xm1 = xp0[-1*3072]; }
  #pragma unroll 4
  for (int tt=0; tt<CT; tt++){
    const float dv = dp[(size_t)tt*D_INNER];
    const float xc = xp0[(size_t)tt*3072];
    const float zv = zp[(size_t)tt*3072];
    float ua = cbv;
    ua += xm3*cwv.x; ua += xm2*cwv.y; ua += xm1*cwv.z; ua += xc*cwv.w;
    const float uv = siluf_(ua);
    xm3 = xm2; xm2 = xm1; xm1 = xc;
    const float4 B0 = *(const float4*)(bp + (size_t)tt*32);
    const float4 B1 = *(const float4*)(bp + (size_t)tt*32 + 4);
    const float4 C0 = *(const float4*)(bp + (size_t)tt*32 + 16);
    const float4 C1 = *(const float4*)(bp + (size_t)tt*32 + 20);
    const float Bv[8] = {B0.x,B0.y,B0.z,B0.w,B1.x,B1.y,B1.z,B1.w};
    const float Cv[8] = {C0.x,C0.y,C0.z,C0.w,C1.x,C1.y,C1.z,C1.w};
    const float du = dv*uv;
    float pp = 0.f;
    #pragma unroll
    for (int n=0;n<8;n++){
      const float dA = __expf(dv*Av[n]);
      h[n] = dA*h[n] + du*Bv[n];
      pp += h[n]*Cv[n];
    }
    const float ptot = pp + __shfl_xor(pp, 1);
    if (nh == 0)
      yp[(size_t)tt*D_INNER] = f2bf((ptot + uv*Dv)*siluf_(zv));
  }
}

// ---------------- fused: [out_proj partial-reduce +] residual add + RMSNorm [+ weight casts] ----------------
__global__ __launch_bounds__(256) void fused_norm_cast(
    float* __restrict__ resid, const float* __restrict__ P0, const float* __restrict__ P1,
    const float* __restrict__ w, unsigned short* __restrict__ obf, float* __restrict__ ofp,
    const float* __restrict__ cin1, unsigned short* __restrict__ co1, int cn1, int cnb1,
    const float* __restrict__ cin2, unsigned short* __restrict__ co2, int cn2)
{
  const int blk = blockIdx.x;
  if (blk >= 2048){
    const int cb = blk - 2048;
    const float* in; unsigned short* o; int i4;
    if (cb < cnb1){ in = cin1; o = co1; i4 = (cb*256 + threadIdx.x)*4; if (i4 >= cn1) return; }
    else { in = cin2; o = co2; i4 = ((cb-cnb1)*256 + threadIdx.x)*4; if (i4 >= cn2) return; }
    float4 v = *(const float4*)(in + i4);
    ushort4 r;
    r.x = f2bf(v.x); r.y = f2bf(v.y); r.z = f2bf(v.z); r.w = f2bf(v.w);
    *(ushort4*)(o + i4) = r;
    return;
  }
  const int row = blk;
  const int tid = threadIdx.x;
  float v[3];
  float ss = 0.f;
  #pragma unroll
  for (int i=0;i<3;i++){
    const int c = tid + i*256;
    const size_t idx = (size_t)row*768 + c;
    float r = resid[idx];
    if (P0) r += P0[idx] + P1[idx];
    v[i] = r;
    ss += r*r;
  }
  #pragma unroll
  for (int off=32; off>=1; off>>=1) ss += __shfl_xor(ss, off);
  __shared__ float sred[4];
  const int lane = tid & 63, wv = tid >> 6;
  if (lane == 0) sred[wv] = ss;
  __syncthreads();
  const float tot = sred[0]+sred[1]+sred[2]+sred[3];
  const float scale = rsqrtf(tot*(1.0f/768.0f) + 1e-5f);
  #pragma unroll
  for (int i=0;i<3;i++){
    const int c = tid + i*256;
    const size_t idx = (size_t)row*768 + c;
    if (P0) resid[idx] = v[i];
    const float o = v[i]*scale*w[c];
    if (obf) obf[idx] = f2bf(o);
    else     ofp[idx] = o;
  }
}

// ---------------- mean pool stage 1 ----------------
__global__ __launch_bounds__(256) void pool_partial(const float* __restrict__ normed,
                                                    float* __restrict__ part){
  const int i = blockIdx.x*256 + threadIdx.x;    // (b,m) flat, 0..3071
  const int s = blockIdx.y;
  const int b = i / 768, m = i % 768;
  float sum = 0.f;
  const float* p = normed + ((size_t)b*T_SZ + s*32)*768 + m;
  #pragma unroll
  for (int t=0; t<32; t++) sum += p[(size_t)t*768];
  part[s*3072 + i] = sum;
}

// ---------------- fused pool-final + classifier: out (4,10) ----------------
__global__ __launch_bounds__(256) void pool_cls(const float* __restrict__ part,
                                                const float* __restrict__ cw,
                                                const float* __restrict__ cb,
                                                float* __restrict__ out){
  __shared__ float ls[768];
  const int b = blockIdx.x;
  const int tid = threadIdx.x;
  #pragma unroll
  for (int i=0;i<3;i++){
    const int m = tid + i*256;
    float s = 0.f;
    #pragma unroll
    for (int c=0;c<16;c++) s += part[c*3072 + b*768 + m];
    ls[m] = s * (1.0f/T_SZ);
  }
  __syncthreads();
  const int wave = tid >> 6, lane = tid & 63;
  for (int o = wave; o < 10; o += 4){
    float s = 0.f;
    for (int k = lane; k < 768; k += 64) s += ls[k]*cw[o*768 + k];
    #pragma unroll
    for (int off=32; off>=1; off>>=1) s += __shfl_xor(s, off);
    if (lane == 0) out[b*10 + o] = s + cb[o];
  }
}

extern "C" void kernel_launch(void* const* d_in, const int* in_sizes, int n_in,
                              void* d_out, int out_size, void* d_ws, size_t ws_size,
                              hipStream_t stream) {
  const float* x         = (const float*)d_in[0];
  const float* in_proj_w = (const float*)d_in[1];
  const float* conv_w    = (const float*)d_in[2];
  const float* conv_b    = (const float*)d_in[3];
  const float* x_proj_w  = (const float*)d_in[4];
  const float* dt_proj_w = (const float*)d_in[5];
  const float* dt_proj_b = (const float*)d_in[6];
  const float* A_log     = (const float*)d_in[7];
  const float* D_param   = (const float*)d_in[8];
  const float* out_proj_w= (const float*)d_in[9];
  const float* norm_w    = (const float*)d_in[10];
  const float* norm_f_w  = (const float*)d_in[11];
  const float* inp_w     = (const float*)d_in[12];
  const float* inp_b     = (const float*)d_in[13];
  const float* cls_w     = (const float*)d_in[14];
  const float* cls_b     = (const float*)d_in[15];
  float* out = (float*)d_out;

  char* ws = (char*)d_ws;
  auto carve = [&](size_t nelem)->float* {
    float* p = (float*)ws;
    ws += ((nelem*sizeof(float) + 255)/256)*256;
    return p;
  };
  float* resid  = carve((size_t)ROWS*768);
  float* normed = carve((size_t)ROWS*768);   // bf16 normed / fp32 at final
  float* xz     = carve((size_t)ROWS*3072);
  float* ucv    = carve((size_t)ROWS*1536);  // out_proj partial s=1
  float* xpbc   = carve((size_t)ROWS*32);    // reduced B/C columns for scan
  float* delta  = carve((size_t)ROWS*1536);  // out_proj partial s=0 after scan
  float* ybf_f  = carve((size_t)ROWS*1536/2);     // bf16 y
  float* wbi_f  = carve((size_t)(3072*768)/2);    // per-layer bf16 in_proj w
  float* wbo_f  = carve((size_t)(768*1536)/2);    // per-layer bf16 out_proj w
  float* sdvbuf = carve((size_t)B_SZ*CH*D_INNER);      // chunk dv-sums
  float* Hend   = carve((size_t)B_SZ*CH*D_INNER*16);   // per-chunk local H
  float* xpart  = carve((size_t)XS*ROWS*XP_N);
  float* ppool  = carve((size_t)16*3072);

  unsigned short* normedb = (unsigned short*)normed;
  unsigned short* ybf = (unsigned short*)ybf_f;
  unsigned short* wbi = (unsigned short*)wbi_f;
  unsigned short* wbo = (unsigned short*)wbo_f;

  sgemm_input<<<dim3(12,32), 256, 0, stream>>>(x, inp_w, inp_b, resid);

  for (int l = 0; l < 4; l++){
    fused_norm_cast<<<2048 + 2304 + 1152, 256, 0, stream>>>(
        resid, l ? delta : nullptr, l ? ucv : nullptr,
        norm_w + (size_t)l*768, normedb, nullptr,
        in_proj_w + (size_t)l*3072*768, wbi, 3072*768, 2304,
        out_proj_w + (size_t)l*768*1536, wbo, 768*1536);
    gemm_bf16<<<dim3(24,32), 256, 0, stream>>>(normedb, wbi, xz, ROWS, 3072, 768);
    xproj_conv_splitk<<<dim3(32,XS), 256, 0, stream>>>(
        xz, conv_w + (size_t)l*1536*4, conv_b + (size_t)l*1536,
        x_proj_w + (size_t)l*XP_N*1536, xpart);
    dtproj_fused<<<dim3(32,32), 256, 0, stream>>>(
        xpart, dt_proj_w + (size_t)l*1536*48, dt_proj_b + (size_t)l*1536, delta, xpbc);
    scan_pass1<<<dim3(12,B_SZ,CH-1), 256, 0, stream>>>(
        delta, xz, xpbc, A_log + (size_t)l*1536*16,
        conv_w + (size_t)l*1536*4, conv_b + (size_t)l*1536, sdvbuf, Hend);
    scan_pass3<<<dim3(12,B_SZ,CH), 256, 0, stream>>>(
        delta, xz, xpbc, A_log + (size_t)l*1536*16,
        conv_w + (size_t)l*1536*4, conv_b + (size_t)l*1536,
        D_param + (size_t)l*1536, sdvbuf, Hend, ybf);
    gemm_bf16_sk<<<dim3(6,32,OS), 256, 0, stream>>>(ybf, wbo, delta, ucv, ROWS, 768, 1536);
  }

  fused_norm_cast<<<2048, 256, 0, stream>>>(
      resid, delta, ucv, norm_f_w, nullptr, normed,
      nullptr, nullptr, 0, 0, nullptr, nullptr, 0);
  pool_partial<<<dim3(12,16), 256, 0, stream>>>(normed, ppool);
  pool_cls<<<4, 256, 0, stream>>>(ppool, cls_w, cls_b, out);
}

// Round 9
// 795.325 us; speedup vs baseline: 1.0452x; 1.0452x over previous
//
#include <hip/hip_runtime.h>
#include <math.h>

#define D_MODEL 768
#define D_INNER 1536
#define B_SZ 4
#define T_SZ 512
#define ROWS (B_SZ*T_SZ)   // 2048
#define XP_N 80
#define CH 32              // scan chunks
#define CT 16              // T per chunk
#define XS 8               // x_proj split-K factor
#define XKC (D_INNER/XS)   // 192
#define OS 2               // out_proj split-K factor
#define OKC (D_INNER/OS)   // 768
#define MN_OUT (ROWS*768)  // 1572864

typedef __attribute__((ext_vector_type(8))) short bf16x8;
typedef __attribute__((ext_vector_type(4))) float f32x4;

// async global->LDS, 16B per lane, lane-contiguous LDS destination
#define GLL(g, l) __builtin_amdgcn_global_load_lds( \
    (const __attribute__((address_space(1))) void*)(g), \
    (__attribute__((address_space(3))) void*)(l), 16, 0, 0)

__device__ __forceinline__ float sigmoidf_(float x){ return 1.0f/(1.0f+__expf(-x)); }
__device__ __forceinline__ float siluf_(float x){ return x*sigmoidf_(x); }
__device__ __forceinline__ unsigned short f2bf(float f){
  unsigned u = __builtin_bit_cast(unsigned, f);
  u = (u + 0x7FFFu + ((u >> 16) & 1u)) >> 16;   // RNE
  return (unsigned short)u;
}

// ---------------- bf16 MFMA GEMM, 64x128 tile, double-buffered 2-phase ----------
__global__ __launch_bounds__(256) void gemm_bf16(
    const unsigned short* __restrict__ A, const unsigned short* __restrict__ Wb,
    float* __restrict__ C, int M, int N, int K)
{
  __shared__ unsigned short As[2][64*32];    // 2 x 4 KB
  __shared__ unsigned short Ws[2][128*32];   // 2 x 8 KB
  const int tid = threadIdx.x;
  const int bm = blockIdx.y*64, bn = blockIdx.x*128;
  const int wave = tid >> 6, lane = tid & 63;
  const int wn = wave*32;
  const int fr = lane & 15, quad = lane >> 4;
  f32x4 acc[4][2] = {};
  const int chunk = wave*64 + lane;          // 0..255
  const int row0 = chunk >> 2;               // 0..63
  const int khp  = chunk & 3;
  const int khl  = (khp + 4 - ((row0 >> 1) & 3)) & 3;
  const unsigned short* Ag = A  + (size_t)(bm + row0)*K + khl*8;
  const unsigned short* Wg = Wb + (size_t)(bn + row0)*K + khl*8;
  const size_t rstep = (size_t)64*K;
  const int wo = wave*512;

  GLL(Ag,         As[0] + wo);
  GLL(Wg,         Ws[0] + wo);
  GLL(Wg + rstep, Ws[0] + wo + 2048);
  asm volatile("s_waitcnt vmcnt(0)" ::: "memory");
  __builtin_amdgcn_sched_barrier(0);
  __builtin_amdgcn_s_barrier();

  int cur = 0;
  for (int k0 = 0; k0 < K; k0 += 32){
    const int nxt = cur ^ 1;
    if (k0 + 32 < K){                        // prefetch next tile
      GLL(Ag + k0 + 32,         As[nxt] + wo);
      GLL(Wg + k0 + 32,         Ws[nxt] + wo);
      GLL(Wg + rstep + k0 + 32, Ws[nxt] + wo + 2048);
    }
    bf16x8 a[4], b[2];
    #pragma unroll
    for (int i=0;i<4;i++){
      const int row = i*16 + fr;
      a[i] = *(const bf16x8*)(As[cur] + row*32 + (((quad + (row>>1)) & 3)*8));
    }
    #pragma unroll
    for (int j=0;j<2;j++){
      const int row = wn + j*16 + fr;
      b[j] = *(const bf16x8*)(Ws[cur] + row*32 + (((quad + (row>>1)) & 3)*8));
    }
    #pragma unroll
    for (int i=0;i<4;i++)
      #pragma unroll
      for (int j=0;j<2;j++)
        acc[i][j] = __builtin_amdgcn_mfma_f32_16x16x32_bf16(a[i], b[j], acc[i][j], 0, 0, 0);
    asm volatile("s_waitcnt vmcnt(0)" ::: "memory");
    __builtin_amdgcn_sched_barrier(0);
    __builtin_amdgcn_s_barrier();
    cur = nxt;
  }
  #pragma unroll
  for (int i=0;i<4;i++){
    #pragma unroll
    for (int r=0;r<4;r++){
      const int row = bm + i*16 + quad*4 + r;
      float* Cp = C + (size_t)row*N + bn + wn + fr;
      #pragma unroll
      for (int j=0;j<2;j++)
        Cp[j*16] = acc[i][j][r];
    }
  }
}

// ---------------- bf16 MFMA GEMM, split-K=2 (out_proj partials), dbuf 2-phase ----
__global__ __launch_bounds__(256) void gemm_bf16_sk(
    const unsigned short* __restrict__ A, const unsigned short* __restrict__ Wb,
    float* __restrict__ P0, float* __restrict__ P1, int M, int N, int K)
{
  __shared__ unsigned short As[2][64*32];
  __shared__ unsigned short Ws[2][128*32];
  const int tid = threadIdx.x;
  const int bm = blockIdx.y*64, bn = blockIdx.x*128;
  const int s = blockIdx.z;
  const int koff = s*OKC;
  const int wave = tid >> 6, lane = tid & 63;
  const int wn = wave*32;
  const int fr = lane & 15, quad = lane >> 4;
  f32x4 acc[4][2] = {};
  const int chunk = wave*64 + lane;
  const int row0 = chunk >> 2;
  const int khp  = chunk & 3;
  const int khl  = (khp + 4 - ((row0 >> 1) & 3)) & 3;
  const unsigned short* Ag = A  + (size_t)(bm + row0)*K + koff + khl*8;
  const unsigned short* Wg = Wb + (size_t)(bn + row0)*K + koff + khl*8;
  const size_t rstep = (size_t)64*K;
  const int wo = wave*512;

  GLL(Ag,         As[0] + wo);
  GLL(Wg,         Ws[0] + wo);
  GLL(Wg + rstep, Ws[0] + wo + 2048);
  asm volatile("s_waitcnt vmcnt(0)" ::: "memory");
  __builtin_amdgcn_sched_barrier(0);
  __builtin_amdgcn_s_barrier();

  int cur = 0;
  for (int k0 = 0; k0 < OKC; k0 += 32){
    const int nxt = cur ^ 1;
    if (k0 + 32 < OKC){
      GLL(Ag + k0 + 32,         As[nxt] + wo);
      GLL(Wg + k0 + 32,         Ws[nxt] + wo);
      GLL(Wg + rstep + k0 + 32, Ws[nxt] + wo + 2048);
    }
    bf16x8 a[4], b[2];
    #pragma unroll
    for (int i=0;i<4;i++){
      const int row = i*16 + fr;
      a[i] = *(const bf16x8*)(As[cur] + row*32 + (((quad + (row>>1)) & 3)*8));
    }
    #pragma unroll
    for (int j=0;j<2;j++){
      const int row = wn + j*16 + fr;
      b[j] = *(const bf16x8*)(Ws[cur] + row*32 + (((quad + (row>>1)) & 3)*8));
    }
    #pragma unroll
    for (int i=0;i<4;i++)
      #pragma unroll
      for (int j=0;j<2;j++)
        acc[i][j] = __builtin_amdgcn_mfma_f32_16x16x32_bf16(a[i], b[j], acc[i][j], 0, 0, 0);
    asm volatile("s_waitcnt vmcnt(0)" ::: "memory");
    __builtin_amdgcn_sched_barrier(0);
    __builtin_amdgcn_s_barrier();
    cur = nxt;
  }
  float* Cb = (s == 0 ? P0 : P1);
  #pragma unroll
  for (int i=0;i<4;i++){
    #pragma unroll
    for (int r=0;r<4;r++){
      const int row = bm + i*16 + quad*4 + r;
      float* Cp = Cb + (size_t)row*N + bn + wn + fr;
      #pragma unroll
      for (int j=0;j<2;j++)
        Cp[j*16] = acc[i][j][r];
    }
  }
}

// ---------------- input SGEMM with fused transpose ----------------
__global__ __launch_bounds__(256) void sgemm_input(
    const float* __restrict__ x, const float* __restrict__ W,
    const float* __restrict__ bias, float* __restrict__ C)
{
  __shared__ float As[16][64];
  __shared__ float Wsh[16][64];
  const int bm = blockIdx.y*64, bn = blockIdx.x*64;
  const int b = bm >> 9, t0 = bm & (T_SZ-1);   // 64-row tiles never straddle b
  const int tid = threadIdx.x;
  const int tx = tid & 15, ty = tid >> 4;
  const int lm = tid & 63, lk = (tid >> 6) << 2;
  float acc[4][4] = {};
  const float* Wp = W + (size_t)(bn+lm)*256 + lk;
  const float* xb = x + ((size_t)b*256)*512 + t0 + lm;
  for (int k0 = 0; k0 < 256; k0 += 16){
    #pragma unroll
    for (int i=0;i<4;i++)
      As[lk+i][lm] = xb[(size_t)(k0+lk+i)*512];   // coalesced along t
    float4 wv = *(const float4*)(Wp + k0);
    Wsh[lk+0][lm]=wv.x; Wsh[lk+1][lm]=wv.y; Wsh[lk+2][lm]=wv.z; Wsh[lk+3][lm]=wv.w;
    __syncthreads();
    #pragma unroll
    for (int k = 0; k < 16; k++){
      float a[4], w[4];
      #pragma unroll
      for (int i=0;i<4;i++) a[i] = As[k][ty*4+i];
      #pragma unroll
      for (int j=0;j<4;j++) w[j] = Wsh[k][tx*4+j];
      #pragma unroll
      for (int i=0;i<4;i++)
        #pragma unroll
        for (int j=0;j<4;j++)
          acc[i][j] += a[i]*w[j];
    }
    __syncthreads();
  }
  #pragma unroll
  for (int i=0;i<4;i++){
    const int r = bm + ty*4 + i;
    #pragma unroll
    for (int j=0;j<4;j++){
      const int n = bn + tx*4 + j;
      C[(size_t)r*768 + n] = acc[i][j] + bias[n];
    }
  }
}

// ---------------- x_proj split-K with fused causal conv + silu ----------------
__global__ __launch_bounds__(256) void xproj_conv_splitk(
    const float* __restrict__ xz, const float* __restrict__ cw,
    const float* __restrict__ cb, const float* __restrict__ W,
    float* __restrict__ part)
{
  __shared__ float As[16][64];
  __shared__ float Wsh[16][80];
  const int bm = blockIdx.x*64;
  const int s = blockIdx.y;
  const int koff = s*XKC;
  const int tid = threadIdx.x;
  const int tx = tid & 15, ty = tid >> 4;
  const int lm = tid & 63, lk = (tid >> 6) << 2;
  float acc[4][5] = {};
  const int row = bm + lm;
  const int t = row & (T_SZ-1);
  for (int k0 = 0; k0 < XKC; k0 += 16){
    const int d0 = koff + k0 + lk;
    float4 cbv = *(const float4*)(cb + d0);
    float cba[4] = {cbv.x, cbv.y, cbv.z, cbv.w};
    float4 tp3 = *(const float4*)(xz + (size_t)row*3072 + d0);
    float4 tp0 = (t>=3) ? *(const float4*)(xz + (size_t)(row-3)*3072 + d0) : make_float4(0.f,0.f,0.f,0.f);
    float4 tp1 = (t>=2) ? *(const float4*)(xz + (size_t)(row-2)*3072 + d0) : make_float4(0.f,0.f,0.f,0.f);
    float4 tp2 = (t>=1) ? *(const float4*)(xz + (size_t)(row-1)*3072 + d0) : make_float4(0.f,0.f,0.f,0.f);
    float a0[4]={tp0.x,tp0.y,tp0.z,tp0.w}, a1[4]={tp1.x,tp1.y,tp1.z,tp1.w};
    float a2[4]={tp2.x,tp2.y,tp2.z,tp2.w}, a3[4]={tp3.x,tp3.y,tp3.z,tp3.w};
    #pragma unroll
    for (int i=0;i<4;i++){
      const float4 w4 = *(const float4*)(cw + (size_t)(d0+i)*4);
      float a = cba[i];
      a += a0[i]*w4.x; a += a1[i]*w4.y; a += a2[i]*w4.z; a += a3[i]*w4.w;
      As[lk+i][lm] = siluf_(a);
    }
    for (int i = tid; i < 320; i += 256){
      const int wr = i % 80, wk = (i / 80) << 2;
      float4 wv = *(const float4*)(W + (size_t)wr*D_INNER + koff + k0 + wk);
      Wsh[wk+0][wr]=wv.x; Wsh[wk+1][wr]=wv.y; Wsh[wk+2][wr]=wv.z; Wsh[wk+3][wr]=wv.w;
    }
    __syncthreads();
    #pragma unroll
    for (int k = 0; k < 16; k++){
      float a[4], w[5];
      #pragma unroll
      for (int i=0;i<4;i++) a[i] = As[k][ty*4+i];
      #pragma unroll
      for (int j=0;j<5;j++) w[j] = Wsh[k][tx*5+j];
      #pragma unroll
      for (int i=0;i<4;i++)
        #pragma unroll
        for (int j=0;j<5;j++)
          acc[i][j] += a[i]*w[j];
    }
    __syncthreads();
  }
  #pragma unroll
  for (int i=0;i<4;i++){
    const int r = bm + ty*4 + i;
    #pragma unroll
    for (int j=0;j<5;j++){
      const int n = tx*5 + j;
      part[((size_t)s*ROWS + r)*XP_N + n] = acc[i][j];
    }
  }
}

// ---------------- dt_proj (reads split-K partials inline) + B/C reduce ----------------
__global__ __launch_bounds__(256) void dtproj_fused(
    const float* __restrict__ part, const float* __restrict__ W,
    const float* __restrict__ bias, float* __restrict__ delta,
    float* __restrict__ xpbc)
{
  if (blockIdx.x >= 24){
    const int i = ((blockIdx.x - 24)*32 + blockIdx.y)*256 + threadIdx.x;  // 0..65535
    const int r = i >> 5, cc = i & 31;
    float ssum = 0.f;
    #pragma unroll
    for (int s2=0;s2<XS;s2++)
      ssum += part[((size_t)s2*ROWS + r)*XP_N + 48 + cc];
    xpbc[(size_t)r*32 + cc] = ssum;
    return;
  }
  __shared__ float As[16][64];
  __shared__ float Wsh[16][64];
  const int bm = blockIdx.y*64, bn = blockIdx.x*64;
  const int tid = threadIdx.x;
  const int tx = tid & 15, ty = tid >> 4;
  const int lm = tid & 63, lk = (tid >> 6) << 2;
  float acc[4][4] = {};
  const float* Ap = part + (size_t)(bm+lm)*XP_N + lk;
  const float* Wp = W + (size_t)(bn+lm)*48 + lk;
  for (int k0 = 0; k0 < 48; k0 += 16){
    float4 av = make_float4(0.f,0.f,0.f,0.f);
    #pragma unroll
    for (int s2=0;s2<XS;s2++){
      const float4 pv = *(const float4*)(Ap + (size_t)s2*ROWS*XP_N + k0);
      av.x += pv.x; av.y += pv.y; av.z += pv.z; av.w += pv.w;
    }
    float4 wv = *(const float4*)(Wp + k0);
    As[lk+0][lm]=av.x; As[lk+1][lm]=av.y; As[lk+2][lm]=av.z; As[lk+3][lm]=av.w;
    Wsh[lk+0][lm]=wv.x; Wsh[lk+1][lm]=wv.y; Wsh[lk+2][lm]=wv.z; Wsh[lk+3][lm]=wv.w;
    __syncthreads();
    #pragma unroll
    for (int k = 0; k < 16; k++){
      float a[4], w[4];
      #pragma unroll
      for (int i=0;i<4;i++) a[i] = As[k][ty*4+i];
      #pragma unroll
      for (int j=0;j<4;j++) w[j] = Wsh[k][tx*4+j];
      #pragma unroll
      for (int i=0;i<4;i++)
        #pragma unroll
        for (int j=0;j<4;j++)
          acc[i][j] += a[i]*w[j];
    }
    __syncthreads();
  }
  #pragma unroll
  for (int i=0;i<4;i++){
    const int r = bm + ty*4 + i;
    #pragma unroll
    for (int j=0;j<4;j++){
      const int n = bn + tx*4 + j;
      float v = acc[i][j] + bias[n];
      v = (v > 20.f) ? v : log1pf(__expf(v));
      delta[(size_t)r*D_INNER + n] = v;
    }
  }
}

// ---------------- chunked selective scan, latency-batched ----------------
// pass1: all t-loop loads hoisted into registers (one latency exposure), B tile
// staged in LDS (block-uniform). Identical FMA order as before.
__global__ __launch_bounds__(256) void scan_pass1(
    const float* __restrict__ delta, const float* __restrict__ xz,
    const float* __restrict__ xpbc, const float* __restrict__ alog,
    const float* __restrict__ cw, const float* __restrict__ cb,
    float* __restrict__ sdvp, float* __restrict__ Hend)
{
  __shared__ float Bs[CT][32];
  const int d = blockIdx.x*256 + threadIdx.x;
  const int b = blockIdx.y, c = blockIdx.z;
  const size_t row0 = (size_t)b*T_SZ + (size_t)c*CT;
  // stage the (block-uniform) B/C tile: CT rows x 32 cols = 2 KB
  for (int i = threadIdx.x; i < CT*32; i += 256)
    Bs[i>>5][i&31] = xpbc[row0*32 + i];
  const float* dp  = delta + row0*D_INNER + d;
  const float* xp0 = xz    + row0*3072 + d;
  // hoist all strided loads (independent -> all in flight together)
  float dvv[CT], xcv[CT];
  #pragma unroll
  for (int tt=0;tt<CT;tt++) dvv[tt] = dp[(size_t)tt*D_INNER];
  #pragma unroll
  for (int tt=0;tt<CT;tt++) xcv[tt] = xp0[(size_t)tt*3072];
  float xm3, xm2, xm1;
  if (c == 0){ xm3 = xm2 = xm1 = 0.f; }
  else { xm3 = xp0[-3*3072]; xm2 = xp0[-2*3072]; xm1 = xp0[-1*3072]; }
  float4 t0 = *(const float4*)(alog + d*16 + 0);
  float4 t1 = *(const float4*)(alog + d*16 + 4);
  float4 t2 = *(const float4*)(alog + d*16 + 8);
  float4 t3 = *(const float4*)(alog + d*16 + 12);
  float Av[16] = {t0.x,t0.y,t0.z,t0.w,t1.x,t1.y,t1.z,t1.w,
                  t2.x,t2.y,t2.z,t2.w,t3.x,t3.y,t3.z,t3.w};
  float h[16];
  #pragma unroll
  for (int n=0;n<16;n++){ Av[n] = -__expf(Av[n]); h[n]=0.f; }
  const float4 cwv = *(const float4*)(cw + (size_t)d*4);
  const float cbv = cb[d];
  __syncthreads();
  float sdv = 0.f;
  #pragma unroll
  for (int tt=0; tt<CT; tt++){
    const float dv = dvv[tt];
    const float xc = xcv[tt];
    float ua = cbv;
    ua += xm3*cwv.x; ua += xm2*cwv.y; ua += xm1*cwv.z; ua += xc*cwv.w;
    const float uv = siluf_(ua);
    xm3 = xm2; xm2 = xm1; xm1 = xc;
    const float du = dv*uv;
    sdv += dv;
    #pragma unroll
    for (int n=0;n<16;n++){
      const float dA = __expf(dv*Av[n]);
      h[n] = dA*h[n] + du*Bs[tt][n];
    }
  }
  sdvp[(size_t)(b*CH+c)*D_INNER + d] = sdv;
  float* Hp = Hend + ((size_t)(b*CH+c)*D_INNER + d)*16;
  *(float4*)(Hp+ 0) = make_float4(h[0],h[1],h[2],h[3]);
  *(float4*)(Hp+ 4) = make_float4(h[4],h[5],h[6],h[7]);
  *(float4*)(Hp+ 8) = make_float4(h[8],h[9],h[10],h[11]);
  *(float4*)(Hp+12) = make_float4(h[12],h[13],h[14],h[15]);
}

// pass3: inline chunk-prefix with 4-wide load batching (identity-padded:
// sdv=0 -> P=1, H=0 -> h unchanged, exact), hoisted t-loop loads, LDS B/C.
__global__ __launch_bounds__(256) void scan_pass3(
    const float* __restrict__ delta, const float* __restrict__ xz,
    const float* __restrict__ xpbc, const float* __restrict__ alog,
    const float* __restrict__ cw, const float* __restrict__ cb,
    const float* __restrict__ Dp, const float* __restrict__ sdvp,
    const float* __restrict__ Hend, unsigned short* __restrict__ yb)
{
  __shared__ float Bs[CT][32];
  const int d = blockIdx.x*256 + threadIdx.x;
  const int b = blockIdx.y, c = blockIdx.z;
  const size_t row0 = (size_t)b*T_SZ + (size_t)c*CT;
  for (int i = threadIdx.x; i < CT*32; i += 256)
    Bs[i>>5][i&31] = xpbc[row0*32 + i];
  float4 t0 = *(const float4*)(alog + d*16 + 0);
  float4 t1 = *(const float4*)(alog + d*16 + 4);
  float4 t2 = *(const float4*)(alog + d*16 + 8);
  float4 t3 = *(const float4*)(alog + d*16 + 12);
  float Av[16] = {t0.x,t0.y,t0.z,t0.w,t1.x,t1.y,t1.z,t1.w,
                  t2.x,t2.y,t2.z,t2.w,t3.x,t3.y,t3.z,t3.w};
  #pragma unroll
  for (int n=0;n<16;n++) Av[n] = -__expf(Av[n]);
  // ---- prefix over prior chunks, 4-wide batched loads ----
  float h[16];
  #pragma unroll
  for (int n=0;n<16;n++) h[n] = 0.f;
  {
    const size_t bases = (size_t)b*CH*D_INNER + d;
    for (int j0 = 0; j0 < c; j0 += 4){
      float sv[4]; float4 H0[4], H1[4], H2[4], H3[4];
      #pragma unroll
      for (int k=0;k<4;k++){
        const int j = j0 + k;
        if (j < c){
          sv[k] = sdvp[bases + (size_t)j*D_INNER];
          const float* Hj = Hend + (bases + (size_t)j*D_INNER)*16;
          H0[k]=*(const float4*)(Hj+0);  H1[k]=*(const float4*)(Hj+4);
          H2[k]=*(const float4*)(Hj+8);  H3[k]=*(const float4*)(Hj+12);
        } else {
          sv[k] = 0.f;   // P = exp(0) = 1, H = 0 -> identity step (exact)
          H0[k]=H1[k]=H2[k]=H3[k]=make_float4(0.f,0.f,0.f,0.f);
        }
      }
      #pragma unroll
      for (int k=0;k<4;k++){
        const float Hv[16] = {H0[k].x,H0[k].y,H0[k].z,H0[k].w,
                              H1[k].x,H1[k].y,H1[k].z,H1[k].w,
                              H2[k].x,H2[k].y,H2[k].z,H2[k].w,
                              H3[k].x,H3[k].y,H3[k].z,H3[k].w};
        #pragma unroll
        for (int n=0;n<16;n++)
          h[n] = __expf(Av[n]*sv[k])*h[n] + Hv[n];
      }
    }
  }
  const float Dv = Dp[d];
  const float* dp  = delta + row0*D_INNER + d;
  const float* xp0 = xz    + row0*3072 + d;
  const float* zp  = xz    + row0*3072 + 1536 + d;
  unsigned short* yp = yb + row0*D_INNER + d;
  // hoist all t-loop loads
  float dvv[CT], xcv[CT], zvv[CT];
  #pragma unroll
  for (int tt=0;tt<CT;tt++) dvv[tt] = dp[(size_t)tt*D_INNER];
  #pragma unroll
  for (int tt=0;tt<CT;tt++) xcv[tt] = xp0[(size_t)tt*3072];
  #pragma unroll
  for (int tt=0;tt<CT;tt++) zvv[tt] = zp[(size_t)tt*3072];
  const float4 cwv = *(const float4*)(cw + (size_t)d*4);
  const float cbv = cb[d];
  float xm3, xm2, xm1;
  if (c == 0){ xm3 = xm2 = xm1 = 0.f; }
  else { xm3 = xp0[-3*3072]; xm2 = xp0[-2*3072]; xm1 = xp0[-1*3072]; }
  __syncthreads();
  #pragma unroll
  for (int tt=0; tt<CT; tt++){
    const float dv = dvv[tt];
    const float xc = xcv[tt];
    const float zv = zvv[tt];
    float ua = cbv;
    ua += xm3*cwv.x; ua += xm2*cwv.y; ua += xm1*cwv.z; ua += xc*cwv.w;
    const float uv = siluf_(ua);
    xm3 = xm2; xm2 = xm1; xm1 = xc;
    const float du = dv*uv;
    float pp = 0.f;
    #pragma unroll
    for (int n=0;n<16;n++){
      const float dA = __expf(dv*Av[n]);
      h[n] = dA*h[n] + du*Bs[tt][n];
      pp += h[n]*Bs[tt][16+n];
    }
    yp[(size_t)tt*D_INNER] = f2bf((pp + uv*Dv)*siluf_(zv));
  }
}

// ---------------- fused: [out_proj partial-reduce +] residual add + RMSNorm [+ weight casts] ----------------
__global__ __launch_bounds__(256) void fused_norm_cast(
    float* __restrict__ resid, const float* __restrict__ P0, const float* __restrict__ P1,
    const float* __restrict__ w, unsigned short* __restrict__ obf, float* __restrict__ ofp,
    const float* __restrict__ cin1, unsigned short* __restrict__ co1, int cn1, int cnb1,
    const float* __restrict__ cin2, unsigned short* __restrict__ co2, int cn2)
{
  const int blk = blockIdx.x;
  if (blk >= 2048){
    const int cb = blk - 2048;
    const float* in; unsigned short* o; int i4;
    if (cb < cnb1){ in = cin1; o = co1; i4 = (cb*256 + threadIdx.x)*4; if (i4 >= cn1) return; }
    else { in = cin2; o = co2; i4 = ((cb-cnb1)*256 + threadIdx.x)*4; if (i4 >= cn2) return; }
    float4 v = *(const float4*)(in + i4);
    ushort4 r;
    r.x = f2bf(v.x); r.y = f2bf(v.y); r.z = f2bf(v.z); r.w = f2bf(v.w);
    *(ushort4*)(o + i4) = r;
    return;
  }
  const int row = blk;
  const int tid = threadIdx.x;
  float v[3];
  float ss = 0.f;
  #pragma unroll
  for (int i=0;i<3;i++){
    const int c = tid + i*256;
    const size_t idx = (size_t)row*768 + c;
    float r = resid[idx];
    if (P0) r += P0[idx] + P1[idx];
    v[i] = r;
    ss += r*r;
  }
  #pragma unroll
  for (int off=32; off>=1; off>>=1) ss += __shfl_xor(ss, off);
  __shared__ float sred[4];
  const int lane = tid & 63, wv = tid >> 6;
  if (lane == 0) sred[wv] = ss;
  __syncthreads();
  const float tot = sred[0]+sred[1]+sred[2]+sred[3];
  const float scale = rsqrtf(tot*(1.0f/768.0f) + 1e-5f);
  #pragma unroll
  for (int i=0;i<3;i++){
    const int c = tid + i*256;
    const size_t idx = (size_t)row*768 + c;
    if (P0) resid[idx] = v[i];
    const float o = v[i]*scale*w[c];
    if (obf) obf[idx] = f2bf(o);
    else     ofp[idx] = o;
  }
}

// ---------------- mean pool stage 1 ----------------
__global__ __launch_bounds__(256) void pool_partial(const float* __restrict__ normed,
                                                    float* __restrict__ part){
  const int i = blockIdx.x*256 + threadIdx.x;    // (b,m) flat, 0..3071
  const int s = blockIdx.y;
  const int b = i / 768, m = i % 768;
  float sum = 0.f;
  const float* p = normed + ((size_t)b*T_SZ + s*32)*768 + m;
  #pragma unroll
  for (int t=0; t<32; t++) sum += p[(size_t)t*768];
  part[s*3072 + i] = sum;
}

// ---------------- fused pool-final + classifier: out (4,10) ----------------
__global__ __launch_bounds__(256) void pool_cls(const float* __restrict__ part,
                                                const float* __restrict__ cw,
                                                const float* __restrict__ cb,
                                                float* __restrict__ out){
  __shared__ float ls[768];
  const int b = blockIdx.x;
  const int tid = threadIdx.x;
  #pragma unroll
  for (int i=0;i<3;i++){
    const int m = tid + i*256;
    float s = 0.f;
    #pragma unroll
    for (int c=0;c<16;c++) s += part[c*3072 + b*768 + m];
    ls[m] = s * (1.0f/T_SZ);
  }
  __syncthreads();
  const int wave = tid >> 6, lane = tid & 63;
  for (int o = wave; o < 10; o += 4){
    float s = 0.f;
    for (int k = lane; k < 768; k += 64) s += ls[k]*cw[o*768 + k];
    #pragma unroll
    for (int off=32; off>=1; off>>=1) s += __shfl_xor(s, off);
    if (lane == 0) out[b*10 + o] = s + cb[o];
  }
}

extern "C" void kernel_launch(void* const* d_in, const int* in_sizes, int n_in,
                              void* d_out, int out_size, void* d_ws, size_t ws_size,
                              hipStream_t stream) {
  const float* x         = (const float*)d_in[0];
  const float* in_proj_w = (const float*)d_in[1];
  const float* conv_w    = (const float*)d_in[2];
  const float* conv_b    = (const float*)d_in[3];
  const float* x_proj_w  = (const float*)d_in[4];
  const float* dt_proj_w = (const float*)d_in[5];
  const float* dt_proj_b = (const float*)d_in[6];
  const float* A_log     = (const float*)d_in[7];
  const float* D_param   = (const float*)d_in[8];
  const float* out_proj_w= (const float*)d_in[9];
  const float* norm_w    = (const float*)d_in[10];
  const float* norm_f_w  = (const float*)d_in[11];
  const float* inp_w     = (const float*)d_in[12];
  const float* inp_b     = (const float*)d_in[13];
  const float* cls_w     = (const float*)d_in[14];
  const float* cls_b     = (const float*)d_in[15];
  float* out = (float*)d_out;

  char* ws = (char*)d_ws;
  auto carve = [&](size_t nelem)->float* {
    float* p = (float*)ws;
    ws += ((nelem*sizeof(float) + 255)/256)*256;
    return p;
  };
  float* resid  = carve((size_t)ROWS*768);
  float* normed = carve((size_t)ROWS*768);   // bf16 normed / fp32 at final
  float* xz     = carve((size_t)ROWS*3072);
  float* ucv    = carve((size_t)ROWS*1536);  // out_proj partial s=1
  float* xpbc   = carve((size_t)ROWS*32);    // reduced B/C columns for scan
  float* delta  = carve((size_t)ROWS*1536);  // out_proj partial s=0 after scan
  float* ybf_f  = carve((size_t)ROWS*1536/2);     // bf16 y
  float* wbi_f  = carve((size_t)(3072*768)/2);    // per-layer bf16 in_proj w
  float* wbo_f  = carve((size_t)(768*1536)/2);    // per-layer bf16 out_proj w
  float* sdvbuf = carve((size_t)B_SZ*CH*D_INNER);      // chunk dv-sums
  float* Hend   = carve((size_t)B_SZ*CH*D_INNER*16);   // per-chunk local H
  float* xpart  = carve((size_t)XS*ROWS*XP_N);
  float* ppool  = carve((size_t)16*3072);

  unsigned short* normedb = (unsigned short*)normed;
  unsigned short* ybf = (unsigned short*)ybf_f;
  unsigned short* wbi = (unsigned short*)wbi_f;
  unsigned short* wbo = (unsigned short*)wbo_f;

  sgemm_input<<<dim3(12,32), 256, 0, stream>>>(x, inp_w, inp_b, resid);

  for (int l = 0; l < 4; l++){
    fused_norm_cast<<<2048 + 2304 + 1152, 256, 0, stream>>>(
        resid, l ? delta : nullptr, l ? ucv : nullptr,
        norm_w + (size_t)l*768, normedb, nullptr,
        in_proj_w + (size_t)l*3072*768, wbi, 3072*768, 2304,
        out_proj_w + (size_t)l*768*1536, wbo, 768*1536);
    gemm_bf16<<<dim3(24,32), 256, 0, stream>>>(normedb, wbi, xz, ROWS, 3072, 768);
    xproj_conv_splitk<<<dim3(32,XS), 256, 0, stream>>>(
        xz, conv_w + (size_t)l*1536*4, conv_b + (size_t)l*1536,
        x_proj_w + (size_t)l*XP_N*1536, xpart);
    dtproj_fused<<<dim3(32,32), 256, 0, stream>>>(
        xpart, dt_proj_w + (size_t)l*1536*48, dt_proj_b + (size_t)l*1536, delta, xpbc);
    scan_pass1<<<dim3(6,B_SZ,CH-1), 256, 0, stream>>>(
        delta, xz, xpbc, A_log + (size_t)l*1536*16,
        conv_w + (size_t)l*1536*4, conv_b + (size_t)l*1536, sdvbuf, Hend);
    scan_pass3<<<dim3(6,B_SZ,CH), 256, 0, stream>>>(
        delta, xz, xpbc, A_log + (size_t)l*1536*16,
        conv_w + (size_t)l*1536*4, conv_b + (size_t)l*1536,
        D_param + (size_t)l*1536, sdvbuf, Hend, ybf);
    gemm_bf16_sk<<<dim3(6,32,OS), 256, 0, stream>>>(ybf, wbo, delta, ucv, ROWS, 768, 1536);
  }

  fused_norm_cast<<<2048, 256, 0, stream>>>(
      resid, delta, ucv, norm_f_w, nullptr, normed,
      nullptr, nullptr, 0, 0, nullptr, nullptr, 0);
  pool_partial<<<dim3(12,16), 256, 0, stream>>>(normed, ppool);
  pool_cls<<<4, 256, 0, stream>>>(ppool, cls_w, cls_b, out);
}

// Round 10
// 777.094 us; speedup vs baseline: 1.0697x; 1.0235x over previous
//
#include <hip/hip_runtime.h>
#include <math.h>

#define D_MODEL 768
#define D_INNER 1536
#define B_SZ 4
#define T_SZ 512
#define ROWS (B_SZ*T_SZ)   // 2048
#define XP_N 80
#define CH 16              // scan chunks
#define CT 32              // T per chunk
#define XS 8               // x_proj split-K factor
#define XKC (D_INNER/XS)   // 192
#define OS 2               // out_proj split-K factor
#define OKC (D_INNER/OS)   // 768
#define MN_OUT (ROWS*768)  // 1572864

typedef __attribute__((ext_vector_type(8))) short bf16x8;
typedef __attribute__((ext_vector_type(4))) float f32x4;

// async global->LDS, 16B per lane, lane-contiguous LDS destination
#define GLL(g, l) __builtin_amdgcn_global_load_lds( \
    (const __attribute__((address_space(1))) void*)(g), \
    (__attribute__((address_space(3))) void*)(l), 16, 0, 0)

__device__ __forceinline__ float sigmoidf_(float x){ return 1.0f/(1.0f+__expf(-x)); }
__device__ __forceinline__ float siluf_(float x){ return x*sigmoidf_(x); }
__device__ __forceinline__ unsigned short f2bf(float f){
  unsigned u = __builtin_bit_cast(unsigned, f);
  u = (u + 0x7FFFu + ((u >> 16) & 1u)) >> 16;   // RNE
  return (unsigned short)u;
}

// ---------------- bf16 MFMA GEMM, 64x128 tile, double-buffered 2-phase ----------
__global__ __launch_bounds__(256) void gemm_bf16(
    const unsigned short* __restrict__ A, const unsigned short* __restrict__ Wb,
    float* __restrict__ C, int M, int N, int K)
{
  __shared__ unsigned short As[2][64*32];    // 2 x 4 KB
  __shared__ unsigned short Ws[2][128*32];   // 2 x 8 KB
  const int tid = threadIdx.x;
  const int bm = blockIdx.y*64, bn = blockIdx.x*128;
  const int wave = tid >> 6, lane = tid & 63;
  const int wn = wave*32;
  const int fr = lane & 15, quad = lane >> 4;
  f32x4 acc[4][2] = {};
  const int chunk = wave*64 + lane;          // 0..255
  const int row0 = chunk >> 2;               // 0..63
  const int khp  = chunk & 3;
  const int khl  = (khp + 4 - ((row0 >> 1) & 3)) & 3;
  const unsigned short* Ag = A  + (size_t)(bm + row0)*K + khl*8;
  const unsigned short* Wg = Wb + (size_t)(bn + row0)*K + khl*8;
  const size_t rstep = (size_t)64*K;
  const int wo = wave*512;

  GLL(Ag,         As[0] + wo);
  GLL(Wg,         Ws[0] + wo);
  GLL(Wg + rstep, Ws[0] + wo + 2048);
  asm volatile("s_waitcnt vmcnt(0)" ::: "memory");
  __builtin_amdgcn_sched_barrier(0);
  __builtin_amdgcn_s_barrier();

  int cur = 0;
  for (int k0 = 0; k0 < K; k0 += 32){
    const int nxt = cur ^ 1;
    if (k0 + 32 < K){                        // prefetch next tile
      GLL(Ag + k0 + 32,         As[nxt] + wo);
      GLL(Wg + k0 + 32,         Ws[nxt] + wo);
      GLL(Wg + rstep + k0 + 32, Ws[nxt] + wo + 2048);
    }
    bf16x8 a[4], b[2];
    #pragma unroll
    for (int i=0;i<4;i++){
      const int row = i*16 + fr;
      a[i] = *(const bf16x8*)(As[cur] + row*32 + (((quad + (row>>1)) & 3)*8));
    }
    #pragma unroll
    for (int j=0;j<2;j++){
      const int row = wn + j*16 + fr;
      b[j] = *(const bf16x8*)(Ws[cur] + row*32 + (((quad + (row>>1)) & 3)*8));
    }
    #pragma unroll
    for (int i=0;i<4;i++)
      #pragma unroll
      for (int j=0;j<2;j++)
        acc[i][j] = __builtin_amdgcn_mfma_f32_16x16x32_bf16(a[i], b[j], acc[i][j], 0, 0, 0);
    asm volatile("s_waitcnt vmcnt(0)" ::: "memory");
    __builtin_amdgcn_sched_barrier(0);
    __builtin_amdgcn_s_barrier();
    cur = nxt;
  }
  #pragma unroll
  for (int i=0;i<4;i++){
    #pragma unroll
    for (int r=0;r<4;r++){
      const int row = bm + i*16 + quad*4 + r;
      float* Cp = C + (size_t)row*N + bn + wn + fr;
      #pragma unroll
      for (int j=0;j<2;j++)
        Cp[j*16] = acc[i][j][r];
    }
  }
}

// ---------------- bf16 MFMA GEMM, split-K=2 (out_proj partials), dbuf 2-phase ----
__global__ __launch_bounds__(256) void gemm_bf16_sk(
    const unsigned short* __restrict__ A, const unsigned short* __restrict__ Wb,
    float* __restrict__ P0, float* __restrict__ P1, int M, int N, int K)
{
  __shared__ unsigned short As[2][64*32];
  __shared__ unsigned short Ws[2][128*32];
  const int tid = threadIdx.x;
  const int bm = blockIdx.y*64, bn = blockIdx.x*128;
  const int s = blockIdx.z;
  const int koff = s*OKC;
  const int wave = tid >> 6, lane = tid & 63;
  const int wn = wave*32;
  const int fr = lane & 15, quad = lane >> 4;
  f32x4 acc[4][2] = {};
  const int chunk = wave*64 + lane;
  const int row0 = chunk >> 2;
  const int khp  = chunk & 3;
  const int khl  = (khp + 4 - ((row0 >> 1) & 3)) & 3;
  const unsigned short* Ag = A  + (size_t)(bm + row0)*K + koff + khl*8;
  const unsigned short* Wg = Wb + (size_t)(bn + row0)*K + koff + khl*8;
  const size_t rstep = (size_t)64*K;
  const int wo = wave*512;

  GLL(Ag,         As[0] + wo);
  GLL(Wg,         Ws[0] + wo);
  GLL(Wg + rstep, Ws[0] + wo + 2048);
  asm volatile("s_waitcnt vmcnt(0)" ::: "memory");
  __builtin_amdgcn_sched_barrier(0);
  __builtin_amdgcn_s_barrier();

  int cur = 0;
  for (int k0 = 0; k0 < OKC; k0 += 32){
    const int nxt = cur ^ 1;
    if (k0 + 32 < OKC){
      GLL(Ag + k0 + 32,         As[nxt] + wo);
      GLL(Wg + k0 + 32,         Ws[nxt] + wo);
      GLL(Wg + rstep + k0 + 32, Ws[nxt] + wo + 2048);
    }
    bf16x8 a[4], b[2];
    #pragma unroll
    for (int i=0;i<4;i++){
      const int row = i*16 + fr;
      a[i] = *(const bf16x8*)(As[cur] + row*32 + (((quad + (row>>1)) & 3)*8));
    }
    #pragma unroll
    for (int j=0;j<2;j++){
      const int row = wn + j*16 + fr;
      b[j] = *(const bf16x8*)(Ws[cur] + row*32 + (((quad + (row>>1)) & 3)*8));
    }
    #pragma unroll
    for (int i=0;i<4;i++)
      #pragma unroll
      for (int j=0;j<2;j++)
        acc[i][j] = __builtin_amdgcn_mfma_f32_16x16x32_bf16(a[i], b[j], acc[i][j], 0, 0, 0);
    asm volatile("s_waitcnt vmcnt(0)" ::: "memory");
    __builtin_amdgcn_sched_barrier(0);
    __builtin_amdgcn_s_barrier();
    cur = nxt;
  }
  float* Cb = (s == 0 ? P0 : P1);
  #pragma unroll
  for (int i=0;i<4;i++){
    #pragma unroll
    for (int r=0;r<4;r++){
      const int row = bm + i*16 + quad*4 + r;
      float* Cp = Cb + (size_t)row*N + bn + wn + fr;
      #pragma unroll
      for (int j=0;j<2;j++)
        Cp[j*16] = acc[i][j][r];
    }
  }
}

// ---------------- input SGEMM with fused transpose ----------------
__global__ __launch_bounds__(256) void sgemm_input(
    const float* __restrict__ x, const float* __restrict__ W,
    const float* __restrict__ bias, float* __restrict__ C)
{
  __shared__ float As[16][64];
  __shared__ float Wsh[16][64];
  const int bm = blockIdx.y*64, bn = blockIdx.x*64;
  const int b = bm >> 9, t0 = bm & (T_SZ-1);   // 64-row tiles never straddle b
  const int tid = threadIdx.x;
  const int tx = tid & 15, ty = tid >> 4;
  const int lm = tid & 63, lk = (tid >> 6) << 2;
  float acc[4][4] = {};
  const float* Wp = W + (size_t)(bn+lm)*256 + lk;
  const float* xb = x + ((size_t)b*256)*512 + t0 + lm;
  for (int k0 = 0; k0 < 256; k0 += 16){
    #pragma unroll
    for (int i=0;i<4;i++)
      As[lk+i][lm] = xb[(size_t)(k0+lk+i)*512];   // coalesced along t
    float4 wv = *(const float4*)(Wp + k0);
    Wsh[lk+0][lm]=wv.x; Wsh[lk+1][lm]=wv.y; Wsh[lk+2][lm]=wv.z; Wsh[lk+3][lm]=wv.w;
    __syncthreads();
    #pragma unroll
    for (int k = 0; k < 16; k++){
      float a[4], w[4];
      #pragma unroll
      for (int i=0;i<4;i++) a[i] = As[k][ty*4+i];
      #pragma unroll
      for (int j=0;j<4;j++) w[j] = Wsh[k][tx*4+j];
      #pragma unroll
      for (int i=0;i<4;i++)
        #pragma unroll
        for (int j=0;j<4;j++)
          acc[i][j] += a[i]*w[j];
    }
    __syncthreads();
  }
  #pragma unroll
  for (int i=0;i<4;i++){
    const int r = bm + ty*4 + i;
    #pragma unroll
    for (int j=0;j<4;j++){
      const int n = bn + tx*4 + j;
      C[(size_t)r*768 + n] = acc[i][j] + bias[n];
    }
  }
}

// ---------------- x_proj split-K with fused causal conv + silu ----------------
__global__ __launch_bounds__(256) void xproj_conv_splitk(
    const float* __restrict__ xz, const float* __restrict__ cw,
    const float* __restrict__ cb, const float* __restrict__ W,
    float* __restrict__ part)
{
  __shared__ float As[16][64];
  __shared__ float Wsh[16][80];
  const int bm = blockIdx.x*64;
  const int s = blockIdx.y;
  const int koff = s*XKC;
  const int tid = threadIdx.x;
  const int tx = tid & 15, ty = tid >> 4;
  const int lm = tid & 63, lk = (tid >> 6) << 2;
  float acc[4][5] = {};
  const int row = bm + lm;
  const int t = row & (T_SZ-1);
  for (int k0 = 0; k0 < XKC; k0 += 16){
    const int d0 = koff + k0 + lk;
    float4 cbv = *(const float4*)(cb + d0);
    float cba[4] = {cbv.x, cbv.y, cbv.z, cbv.w};
    float4 tp3 = *(const float4*)(xz + (size_t)row*3072 + d0);
    float4 tp0 = (t>=3) ? *(const float4*)(xz + (size_t)(row-3)*3072 + d0) : make_float4(0.f,0.f,0.f,0.f);
    float4 tp1 = (t>=2) ? *(const float4*)(xz + (size_t)(row-2)*3072 + d0) : make_float4(0.f,0.f,0.f,0.f);
    float4 tp2 = (t>=1) ? *(const float4*)(xz + (size_t)(row-1)*3072 + d0) : make_float4(0.f,0.f,0.f,0.f);
    float a0[4]={tp0.x,tp0.y,tp0.z,tp0.w}, a1[4]={tp1.x,tp1.y,tp1.z,tp1.w};
    float a2[4]={tp2.x,tp2.y,tp2.z,tp2.w}, a3[4]={tp3.x,tp3.y,tp3.z,tp3.w};
    #pragma unroll
    for (int i=0;i<4;i++){
      const float4 w4 = *(const float4*)(cw + (size_t)(d0+i)*4);
      float a = cba[i];
      a += a0[i]*w4.x; a += a1[i]*w4.y; a += a2[i]*w4.z; a += a3[i]*w4.w;
      As[lk+i][lm] = siluf_(a);
    }
    for (int i = tid; i < 320; i += 256){
      const int wr = i % 80, wk = (i / 80) << 2;
      float4 wv = *(const float4*)(W + (size_t)wr*D_INNER + koff + k0 + wk);
      Wsh[wk+0][wr]=wv.x; Wsh[wk+1][wr]=wv.y; Wsh[wk+2][wr]=wv.z; Wsh[wk+3][wr]=wv.w;
    }
    __syncthreads();
    #pragma unroll
    for (int k = 0; k < 16; k++){
      float a[4], w[5];
      #pragma unroll
      for (int i=0;i<4;i++) a[i] = As[k][ty*4+i];
      #pragma unroll
      for (int j=0;j<5;j++) w[j] = Wsh[k][tx*5+j];
      #pragma unroll
      for (int i=0;i<4;i++)
        #pragma unroll
        for (int j=0;j<5;j++)
          acc[i][j] += a[i]*w[j];
    }
    __syncthreads();
  }
  #pragma unroll
  for (int i=0;i<4;i++){
    const int r = bm + ty*4 + i;
    #pragma unroll
    for (int j=0;j<5;j++){
      const int n = tx*5 + j;
      part[((size_t)s*ROWS + r)*XP_N + n] = acc[i][j];
    }
  }
}

// ---------------- dt_proj (reads split-K partials inline) + B/C reduce ----------------
__global__ __launch_bounds__(256) void dtproj_fused(
    const float* __restrict__ part, const float* __restrict__ W,
    const float* __restrict__ bias, float* __restrict__ delta,
    float* __restrict__ xpbc)
{
  if (blockIdx.x >= 24){
    const int i = ((blockIdx.x - 24)*32 + blockIdx.y)*256 + threadIdx.x;  // 0..65535
    const int r = i >> 5, cc = i & 31;
    float ssum = 0.f;
    #pragma unroll
    for (int s2=0;s2<XS;s2++)
      ssum += part[((size_t)s2*ROWS + r)*XP_N + 48 + cc];
    xpbc[(size_t)r*32 + cc] = ssum;
    return;
  }
  __shared__ float As[16][64];
  __shared__ float Wsh[16][64];
  const int bm = blockIdx.y*64, bn = blockIdx.x*64;
  const int tid = threadIdx.x;
  const int tx = tid & 15, ty = tid >> 4;
  const int lm = tid & 63, lk = (tid >> 6) << 2;
  float acc[4][4] = {};
  const float* Ap = part + (size_t)(bm+lm)*XP_N + lk;
  const float* Wp = W + (size_t)(bn+lm)*48 + lk;
  for (int k0 = 0; k0 < 48; k0 += 16){
    float4 av = make_float4(0.f,0.f,0.f,0.f);
    #pragma unroll
    for (int s2=0;s2<XS;s2++){
      const float4 pv = *(const float4*)(Ap + (size_t)s2*ROWS*XP_N + k0);
      av.x += pv.x; av.y += pv.y; av.z += pv.z; av.w += pv.w;
    }
    float4 wv = *(const float4*)(Wp + k0);
    As[lk+0][lm]=av.x; As[lk+1][lm]=av.y; As[lk+2][lm]=av.z; As[lk+3][lm]=av.w;
    Wsh[lk+0][lm]=wv.x; Wsh[lk+1][lm]=wv.y; Wsh[lk+2][lm]=wv.z; Wsh[lk+3][lm]=wv.w;
    __syncthreads();
    #pragma unroll
    for (int k = 0; k < 16; k++){
      float a[4], w[4];
      #pragma unroll
      for (int i=0;i<4;i++) a[i] = As[k][ty*4+i];
      #pragma unroll
      for (int j=0;j<4;j++) w[j] = Wsh[k][tx*4+j];
      #pragma unroll
      for (int i=0;i<4;i++)
        #pragma unroll
        for (int j=0;j<4;j++)
          acc[i][j] += a[i]*w[j];
    }
    __syncthreads();
  }
  #pragma unroll
  for (int i=0;i<4;i++){
    const int r = bm + ty*4 + i;
    #pragma unroll
    for (int j=0;j<4;j++){
      const int n = bn + tx*4 + j;
      float v = acc[i][j] + bias[n];
      v = (v > 20.f) ? v : log1pf(__expf(v));
      delta[(size_t)r*D_INNER + n] = v;
    }
  }
}

// ---------------- chunked selective scan, latency-batched, CH=16/CT=32 ----------
// pass1: all t-loop loads hoisted (one latency exposure), B tile in LDS.
__global__ __launch_bounds__(256) void scan_pass1(
    const float* __restrict__ delta, const float* __restrict__ xz,
    const float* __restrict__ xpbc, const float* __restrict__ alog,
    const float* __restrict__ cw, const float* __restrict__ cb,
    float* __restrict__ sdvp, float* __restrict__ Hend)
{
  __shared__ float Bs[CT][32];
  const int d = blockIdx.x*256 + threadIdx.x;
  const int b = blockIdx.y, c = blockIdx.z;
  const size_t row0 = (size_t)b*T_SZ + (size_t)c*CT;
  for (int i = threadIdx.x; i < CT*32; i += 256)
    Bs[i>>5][i&31] = xpbc[row0*32 + i];
  const float* dp  = delta + row0*D_INNER + d;
  const float* xp0 = xz    + row0*3072 + d;
  float4 t0 = *(const float4*)(alog + d*16 + 0);
  float4 t1 = *(const float4*)(alog + d*16 + 4);
  float4 t2 = *(const float4*)(alog + d*16 + 8);
  float4 t3 = *(const float4*)(alog + d*16 + 12);
  float Av[16] = {t0.x,t0.y,t0.z,t0.w,t1.x,t1.y,t1.z,t1.w,
                  t2.x,t2.y,t2.z,t2.w,t3.x,t3.y,t3.z,t3.w};
  float h[16];
  #pragma unroll
  for (int n=0;n<16;n++){ Av[n] = -__expf(Av[n]); h[n]=0.f; }
  const float4 cwv = *(const float4*)(cw + (size_t)d*4);
  const float cbv = cb[d];
  float xm3, xm2, xm1;
  if (c == 0){ xm3 = xm2 = xm1 = 0.f; }
  else { xm3 = xp0[-3*3072]; xm2 = xp0[-2*3072]; xm1 = xp0[-1*3072]; }
  __syncthreads();
  float sdv = 0.f;
  // two 16-deep halves: hoisted loads per half (keeps VGPR bounded)
  #pragma unroll
  for (int hh=0; hh<2; hh++){
    float dvv[16], xcv[16];
    const int tb = hh*16;
    #pragma unroll
    for (int k=0;k<16;k++) dvv[k] = dp[(size_t)(tb+k)*D_INNER];
    #pragma unroll
    for (int k=0;k<16;k++) xcv[k] = xp0[(size_t)(tb+k)*3072];
    #pragma unroll
    for (int k=0; k<16; k++){
      const int tt = tb + k;
      const float dv = dvv[k];
      const float xc = xcv[k];
      float ua = cbv;
      ua += xm3*cwv.x; ua += xm2*cwv.y; ua += xm1*cwv.z; ua += xc*cwv.w;
      const float uv = siluf_(ua);
      xm3 = xm2; xm2 = xm1; xm1 = xc;
      const float du = dv*uv;
      sdv += dv;
      #pragma unroll
      for (int n=0;n<16;n++){
        const float dA = __expf(dv*Av[n]);
        h[n] = dA*h[n] + du*Bs[tt][n];
      }
    }
  }
  sdvp[(size_t)(b*CH+c)*D_INNER + d] = sdv;
  float* Hp = Hend + ((size_t)(b*CH+c)*D_INNER + d)*16;
  *(float4*)(Hp+ 0) = make_float4(h[0],h[1],h[2],h[3]);
  *(float4*)(Hp+ 4) = make_float4(h[4],h[5],h[6],h[7]);
  *(float4*)(Hp+ 8) = make_float4(h[8],h[9],h[10],h[11]);
  *(float4*)(Hp+12) = make_float4(h[12],h[13],h[14],h[15]);
}

// pass3: inline chunk-prefix (4-wide batched, identity-padded), two-half hoisted
// t-loop, LDS B/C. Same FMA order as the scan_combine+pass3 pair -> bit-identical.
__global__ __launch_bounds__(256) void scan_pass3(
    const float* __restrict__ delta, const float* __restrict__ xz,
    const float* __restrict__ xpbc, const float* __restrict__ alog,
    const float* __restrict__ cw, const float* __restrict__ cb,
    const float* __restrict__ Dp, const float* __restrict__ sdvp,
    const float* __restrict__ Hend, unsigned short* __restrict__ yb)
{
  __shared__ float Bs[CT][32];
  const int d = blockIdx.x*256 + threadIdx.x;
  const int b = blockIdx.y, c = blockIdx.z;
  const size_t row0 = (size_t)b*T_SZ + (size_t)c*CT;
  for (int i = threadIdx.x; i < CT*32; i += 256)
    Bs[i>>5][i&31] = xpbc[row0*32 + i];
  float4 t0 = *(const float4*)(alog + d*16 + 0);
  float4 t1 = *(const float4*)(alog + d*16 + 4);
  float4 t2 = *(const float4*)(alog + d*16 + 8);
  float4 t3 = *(const float4*)(alog + d*16 + 12);
  float Av[16] = {t0.x,t0.y,t0.z,t0.w,t1.x,t1.y,t1.z,t1.w,
                  t2.x,t2.y,t2.z,t2.w,t3.x,t3.y,t3.z,t3.w};
  #pragma unroll
  for (int n=0;n<16;n++) Av[n] = -__expf(Av[n]);
  // ---- prefix over prior chunks, 4-wide batched loads ----
  float h[16];
  #pragma unroll
  for (int n=0;n<16;n++) h[n] = 0.f;
  {
    const size_t bases = (size_t)b*CH*D_INNER + d;
    for (int j0 = 0; j0 < c; j0 += 4){
      float sv[4]; float4 H0[4], H1[4], H2[4], H3[4];
      #pragma unroll
      for (int k=0;k<4;k++){
        const int j = j0 + k;
        if (j < c){
          sv[k] = sdvp[bases + (size_t)j*D_INNER];
          const float* Hj = Hend + (bases + (size_t)j*D_INNER)*16;
          H0[k]=*(const float4*)(Hj+0);  H1[k]=*(const float4*)(Hj+4);
          H2[k]=*(const float4*)(Hj+8);  H3[k]=*(const float4*)(Hj+12);
        } else {
          sv[k] = 0.f;   // P = exp(0) = 1, H = 0 -> identity step (exact)
          H0[k]=H1[k]=H2[k]=H3[k]=make_float4(0.f,0.f,0.f,0.f);
        }
      }
      #pragma unroll
      for (int k=0;k<4;k++){
        const float Hv[16] = {H0[k].x,H0[k].y,H0[k].z,H0[k].w,
                              H1[k].x,H1[k].y,H1[k].z,H1[k].w,
                              H2[k].x,H2[k].y,H2[k].z,H2[k].w,
                              H3[k].x,H3[k].y,H3[k].z,H3[k].w};
        #pragma unroll
        for (int n=0;n<16;n++)
          h[n] = __expf(Av[n]*sv[k])*h[n] + Hv[n];
      }
    }
  }
  const float Dv = Dp[d];
  const float* dp  = delta + row0*D_INNER + d;
  const float* xp0 = xz    + row0*3072 + d;
  const float* zp  = xz    + row0*3072 + 1536 + d;
  unsigned short* yp = yb + row0*D_INNER + d;
  const float4 cwv = *(const float4*)(cw + (size_t)d*4);
  const float cbv = cb[d];
  float xm3, xm2, xm1;
  if (c == 0){ xm3 = xm2 = xm1 = 0.f; }
  else { xm3 = xp0[-3*3072]; xm2 = xp0[-2*3072]; xm1 = xp0[-1*3072]; }
  __syncthreads();
  // two 16-deep halves: hoisted loads per half
  #pragma unroll
  for (int hh=0; hh<2; hh++){
    const int tb = hh*16;
    float dvv[16], xcv[16], zvv[16];
    #pragma unroll
    for (int k=0;k<16;k++) dvv[k] = dp[(size_t)(tb+k)*D_INNER];
    #pragma unroll
    for (int k=0;k<16;k++) xcv[k] = xp0[(size_t)(tb+k)*3072];
    #pragma unroll
    for (int k=0;k<16;k++) zvv[k] = zp[(size_t)(tb+k)*3072];
    #pragma unroll
    for (int k=0; k<16; k++){
      const int tt = tb + k;
      const float dv = dvv[k];
      const float xc = xcv[k];
      const float zv = zvv[k];
      float ua = cbv;
      ua += xm3*cwv.x; ua += xm2*cwv.y; ua += xm1*cwv.z; ua += xc*cwv.w;
      const float uv = siluf_(ua);
      xm3 = xm2; xm2 = xm1; xm1 = xc;
      const float du = dv*uv;
      float pp = 0.f;
      #pragma unroll
      for (int n=0;n<16;n++){
        const float dA = __expf(dv*Av[n]);
        h[n] = dA*h[n] + du*Bs[tt][n];
        pp += h[n]*Bs[tt][16+n];
      }
      yp[(size_t)tt*D_INNER] = f2bf((pp + uv*Dv)*siluf_(zv));
    }
  }
}

// ---------------- fused: [out_proj partial-reduce +] residual add + RMSNorm [+ weight casts] ----------------
__global__ __launch_bounds__(256) void fused_norm_cast(
    float* __restrict__ resid, const float* __restrict__ P0, const float* __restrict__ P1,
    const float* __restrict__ w, unsigned short* __restrict__ obf, float* __restrict__ ofp,
    const float* __restrict__ cin1, unsigned short* __restrict__ co1, int cn1, int cnb1,
    const float* __restrict__ cin2, unsigned short* __restrict__ co2, int cn2)
{
  const int blk = blockIdx.x;
  if (blk >= 2048){
    const int cb = blk - 2048;
    const float* in; unsigned short* o; int i4;
    if (cb < cnb1){ in = cin1; o = co1; i4 = (cb*256 + threadIdx.x)*4; if (i4 >= cn1) return; }
    else { in = cin2; o = co2; i4 = ((cb-cnb1)*256 + threadIdx.x)*4; if (i4 >= cn2) return; }
    float4 v = *(const float4*)(in + i4);
    ushort4 r;
    r.x = f2bf(v.x); r.y = f2bf(v.y); r.z = f2bf(v.z); r.w = f2bf(v.w);
    *(ushort4*)(o + i4) = r;
    return;
  }
  const int row = blk;
  const int tid = threadIdx.x;
  float v[3];
  float ss = 0.f;
  #pragma unroll
  for (int i=0;i<3;i++){
    const int c = tid + i*256;
    const size_t idx = (size_t)row*768 + c;
    float r = resid[idx];
    if (P0) r += P0[idx] + P1[idx];
    v[i] = r;
    ss += r*r;
  }
  #pragma unroll
  for (int off=32; off>=1; off>>=1) ss += __shfl_xor(ss, off);
  __shared__ float sred[4];
  const int lane = tid & 63, wv = tid >> 6;
  if (lane == 0) sred[wv] = ss;
  __syncthreads();
  const float tot = sred[0]+sred[1]+sred[2]+sred[3];
  const float scale = rsqrtf(tot*(1.0f/768.0f) + 1e-5f);
  #pragma unroll
  for (int i=0;i<3;i++){
    const int c = tid + i*256;
    const size_t idx = (size_t)row*768 + c;
    if (P0) resid[idx] = v[i];
    const float o = v[i]*scale*w[c];
    if (obf) obf[idx] = f2bf(o);
    else     ofp[idx] = o;
  }
}

// ---------------- mean pool stage 1 ----------------
__global__ __launch_bounds__(256) void pool_partial(const float* __restrict__ normed,
                                                    float* __restrict__ part){
  const int i = blockIdx.x*256 + threadIdx.x;    // (b,m) flat, 0..3071
  const int s = blockIdx.y;
  const int b = i / 768, m = i % 768;
  float sum = 0.f;
  const float* p = normed + ((size_t)b*T_SZ + s*32)*768 + m;
  #pragma unroll
  for (int t=0; t<32; t++) sum += p[(size_t)t*768];
  part[s*3072 + i] = sum;
}

// ---------------- fused pool-final + classifier: out (4,10) ----------------
__global__ __launch_bounds__(256) void pool_cls(const float* __restrict__ part,
                                                const float* __restrict__ cw,
                                                const float* __restrict__ cb,
                                                float* __restrict__ out){
  __shared__ float ls[768];
  const int b = blockIdx.x;
  const int tid = threadIdx.x;
  #pragma unroll
  for (int i=0;i<3;i++){
    const int m = tid + i*256;
    float s = 0.f;
    #pragma unroll
    for (int c=0;c<16;c++) s += part[c*3072 + b*768 + m];
    ls[m] = s * (1.0f/T_SZ);
  }
  __syncthreads();
  const int wave = tid >> 6, lane = tid & 63;
  for (int o = wave; o < 10; o += 4){
    float s = 0.f;
    for (int k = lane; k < 768; k += 64) s += ls[k]*cw[o*768 + k];
    #pragma unroll
    for (int off=32; off>=1; off>>=1) s += __shfl_xor(s, off);
    if (lane == 0) out[b*10 + o] = s + cb[o];
  }
}

extern "C" void kernel_launch(void* const* d_in, const int* in_sizes, int n_in,
                              void* d_out, int out_size, void* d_ws, size_t ws_size,
                              hipStream_t stream) {
  const float* x         = (const float*)d_in[0];
  const float* in_proj_w = (const float*)d_in[1];
  const float* conv_w    = (const float*)d_in[2];
  const float* conv_b    = (const float*)d_in[3];
  const float* x_proj_w  = (const float*)d_in[4];
  const float* dt_proj_w = (const float*)d_in[5];
  const float* dt_proj_b = (const float*)d_in[6];
  const float* A_log     = (const float*)d_in[7];
  const float* D_param   = (const float*)d_in[8];
  const float* out_proj_w= (const float*)d_in[9];
  const float* norm_w    = (const float*)d_in[10];
  const float* norm_f_w  = (const float*)d_in[11];
  const float* inp_w     = (const float*)d_in[12];
  const float* inp_b     = (const float*)d_in[13];
  const float* cls_w     = (const float*)d_in[14];
  const float* cls_b     = (const float*)d_in[15];
  float* out = (float*)d_out;

  char* ws = (char*)d_ws;
  auto carve = [&](size_t nelem)->float* {
    float* p = (float*)ws;
    ws += ((nelem*sizeof(float) + 255)/256)*256;
    return p;
  };
  float* resid  = carve((size_t)ROWS*768);
  float* normed = carve((size_t)ROWS*768);   // bf16 normed / fp32 at final
  float* xz     = carve((size_t)ROWS*3072);
  float* ucv    = carve((size_t)ROWS*1536);  // out_proj partial s=1
  float* xpbc   = carve((size_t)ROWS*32);    // reduced B/C columns for scan
  float* delta  = carve((size_t)ROWS*1536);  // out_proj partial s=0 after scan
  float* ybf_f  = carve((size_t)ROWS*1536/2);     // bf16 y
  float* wbi_f  = carve((size_t)(3072*768)/2);    // per-layer bf16 in_proj w
  float* wbo_f  = carve((size_t)(768*1536)/2);    // per-layer bf16 out_proj w
  float* sdvbuf = carve((size_t)B_SZ*CH*D_INNER);      // chunk dv-sums
  float* Hend   = carve((size_t)B_SZ*CH*D_INNER*16);   // per-chunk local H
  float* xpart  = carve((size_t)XS*ROWS*XP_N);
  float* ppool  = carve((size_t)16*3072);

  unsigned short* normedb = (unsigned short*)normed;
  unsigned short* ybf = (unsigned short*)ybf_f;
  unsigned short* wbi = (unsigned short*)wbi_f;
  unsigned short* wbo = (unsigned short*)wbo_f;

  sgemm_input<<<dim3(12,32), 256, 0, stream>>>(x, inp_w, inp_b, resid);

  for (int l = 0; l < 4; l++){
    fused_norm_cast<<<2048 + 2304 + 1152, 256, 0, stream>>>(
        resid, l ? delta : nullptr, l ? ucv : nullptr,
        norm_w + (size_t)l*768, normedb, nullptr,
        in_proj_w + (size_t)l*3072*768, wbi, 3072*768, 2304,
        out_proj_w + (size_t)l*768*1536, wbo, 768*1536);
    gemm_bf16<<<dim3(24,32), 256, 0, stream>>>(normedb, wbi, xz, ROWS, 3072, 768);
    xproj_conv_splitk<<<dim3(32,XS), 256, 0, stream>>>(
        xz, conv_w + (size_t)l*1536*4, conv_b + (size_t)l*1536,
        x_proj_w + (size_t)l*XP_N*1536, xpart);
    dtproj_fused<<<dim3(32,32), 256, 0, stream>>>(
        xpart, dt_proj_w + (size_t)l*1536*48, dt_proj_b + (size_t)l*1536, delta, xpbc);
    scan_pass1<<<dim3(6,B_SZ,CH-1), 256, 0, stream>>>(
        delta, xz, xpbc, A_log + (size_t)l*1536*16,
        conv_w + (size_t)l*1536*4, conv_b + (size_t)l*1536, sdvbuf, Hend);
    scan_pass3<<<dim3(6,B_SZ,CH), 256, 0, stream>>>(
        delta, xz, xpbc, A_log + (size_t)l*1536*16,
        conv_w + (size_t)l*1536*4, conv_b + (size_t)l*1536,
        D_param + (size_t)l*1536, sdvbuf, Hend, ybf);
    gemm_bf16_sk<<<dim3(6,32,OS), 256, 0, stream>>>(ybf, wbo, delta, ucv, ROWS, 768, 1536);
  }

  fused_norm_cast<<<2048, 256, 0, stream>>>(
      resid, delta, ucv, norm_f_w, nullptr, normed,
      nullptr, nullptr, 0, 0, nullptr, nullptr, 0);
  pool_partial<<<dim3(12,16), 256, 0, stream>>>(normed, ppool);
  pool_cls<<<4, 256, 0, stream>>>(ppool, cls_w, cls_b, out);
}